// Round 10
// baseline (101.009 us; speedup 1.0000x reference)
//
#include <hip/hip_runtime.h>
#include <hip/hip_bf16.h>

// Problem constants
#define B_ 2
#define C_ 256
#define O_ 256
#define T_ 16
#define H_ 64
#define W_ 64

typedef __bf16 bf16x8 __attribute__((ext_vector_type(8)));
typedef float  f32x4  __attribute__((ext_vector_type(4)));

// ---------------- single fused kernel, zero in-loop barriers ----------------
// Grid 1024 = wb(4) x hg(8) x bt(32). Block: 512 thr = 8 waves.
// Wave tile 32o x 16w; block covers 256o x 16w x 8h. 4 blocks/CU = 32
// waves/CU (max occupancy TLP).
// A (W3d) in regs: af[2][8] = 64 VGPR (direct f32 load + cvt, L2-resident).
// B (th*tw) in regs: twf[8] = 32 VGPR (lane's own w-column), scaled per h by
//   th via LDS *broadcast* reads (conflict-free). NO LDS B-tile -> NO
//   in-loop __syncthreads -> no lockstep vmcnt(0) drains; stores self-
//   throttle while 32 waves/CU keep all pipes fed (r9 lesson: barrier-per-h
//   lockstep left ~50% of the write-floor time as bubbles).
// obj (1x1 conv1d) computed per block from L2-resident W1d (redundant, ~1us).
__global__ __attribute__((amdgpu_flat_work_group_size(512, 512)))
void fused_kernel(
    const float* __restrict__ fea_th, const float* __restrict__ fea_tw,
    const float* __restrict__ fea_obj,
    const float* __restrict__ heatmap, const float* __restrict__ mask,
    const float* __restrict__ W3d, const float* __restrict__ b3d,
    const float* __restrict__ W1d, const float* __restrict__ b1d,
    float* __restrict__ out) {
    __shared__ __align__(16) float sTh[8 * 256];   // [h][c]
    __shared__ float sFo[256];                     // fea_obj[b,:,t]
    __shared__ float sPb[256];                     // b3d
    __shared__ float sObj[256];                    // conv1d output for (b,t)

    const int tid  = threadIdx.x;
    const int lane = tid & 63;
    const int wv   = tid >> 6;       // 0..7 -> o base wv*32
    const int kgrp = lane >> 4;      // 0..3 -> c sub-slice
    const int l15  = lane & 15;      // -> w within tile / MFMA col

    const int bid = blockIdx.x;
    const int wb = bid & 3, hg = (bid >> 2) & 7, bt = bid >> 5;
    const int b = bt >> 4, t = bt & 15;
    const int h0 = hg * 8, w0 = wb * 16;

    // ---- stage th / fo / pb (first 256 threads; c = tid) ----
    if (tid < 256) {
        const float* thp = fea_th + ((b * C_ + tid) * T_ + t) * H_ + h0;
        float4 v0 = *(const float4*)thp;
        float4 v1 = *(const float4*)(thp + 4);
        sTh[0 * 256 + tid] = v0.x;  sTh[1 * 256 + tid] = v0.y;
        sTh[2 * 256 + tid] = v0.z;  sTh[3 * 256 + tid] = v0.w;
        sTh[4 * 256 + tid] = v1.x;  sTh[5 * 256 + tid] = v1.y;
        sTh[6 * 256 + tid] = v1.z;  sTh[7 * 256 + tid] = v1.w;
        sFo[tid] = fea_obj[(b * C_ + tid) * T_ + t];
        sPb[tid] = b3d[tid];
    }

    // ---- tw -> register fragment: lane's own w = w0+l15, c-slice by kgrp ----
    // twf[ks][j] = tw[c = ks*32 + kgrp*8 + j][w0+l15]   (32 VGPR)
    const float* twp = fea_tw + ((b * C_) * T_ + t) * W_ + w0 + l15;
    bf16x8 twf[8];
#pragma unroll
    for (int ks = 0; ks < 8; ++ks) {
        bf16x8 pk;
#pragma unroll
        for (int j = 0; j < 8; ++j) {
            const int c = ks * 32 + kgrp * 8 + j;
            pk[j] = (__bf16)twp[c * (T_ * W_)];
        }
        twf[ks] = pk;
    }

    // ---- A panel: W3d f32 -> bf16 regs, af[mf][ks] = 64 VGPR ----
    bf16x8 af[2][8];
#pragma unroll
    for (int mf = 0; mf < 2; ++mf)
#pragma unroll
        for (int ks = 0; ks < 8; ++ks) {
            const float* wp = W3d + (wv * 32 + mf * 16 + l15) * C_ +
                              ks * 32 + kgrp * 8;
            const f32x4 a0 = *(const f32x4*)wp;
            const f32x4 a1 = *(const f32x4*)(wp + 4);
            bf16x8 pk;
            pk[0] = (__bf16)a0[0]; pk[1] = (__bf16)a0[1];
            pk[2] = (__bf16)a0[2]; pk[3] = (__bf16)a0[3];
            pk[4] = (__bf16)a1[0]; pk[5] = (__bf16)a1[1];
            pk[6] = (__bf16)a1[2]; pk[7] = (__bf16)a1[3];
            af[mf][ks] = pk;
        }

    __syncthreads();          // sTh / sFo / sPb visible

    // ---- obj[o] = dot(W1d[o,:], fo) + b1d[o]  (first 256 threads) ----
    if (tid < 256) {
        const float4* wrow = (const float4*)(W1d + tid * C_);
        float s = 0.f;
#pragma unroll 8
        for (int cq = 0; cq < C_ / 4; ++cq) {
            const float4 w4 = wrow[cq];
            s += w4.x * sFo[cq * 4 + 0] + w4.y * sFo[cq * 4 + 1] +
                 w4.z * sFo[cq * 4 + 2] + w4.w * sFo[cq * 4 + 3];
        }
        sObj[tid] = s + b1d[tid];
    }
    __syncthreads();          // sObj visible; LAST barrier in the kernel

    const int hmb = (b * T_ + t) * (H_ * W_);
    const int ob0 = wv * 32 + kgrp * 4;

#pragma unroll 1
    for (int hl = 0; hl < 8; ++hl) {
        const int hglb = h0 + hl;
        const int hrow = hmb + hglb * W_ + w0 + l15;
        const float ht = heatmap[hrow];
        const float mk = mask[hrow];

        f32x4 acc[2] = {};
#pragma unroll
        for (int ks = 0; ks < 8; ++ks) {
            // th slice: broadcast LDS read (16 lanes same addr, 4 kgrp regions)
            const float* thp = sTh + hl * 256 + ks * 32 + kgrp * 8;
            const f32x4 th0 = *(const f32x4*)thp;
            const f32x4 th1 = *(const f32x4*)(thp + 4);

            const bf16x8 tw8 = twf[ks];
            bf16x8 pk;
            pk[0] = (__bf16)((float)tw8[0] * th0[0]);
            pk[1] = (__bf16)((float)tw8[1] * th0[1]);
            pk[2] = (__bf16)((float)tw8[2] * th0[2]);
            pk[3] = (__bf16)((float)tw8[3] * th0[3]);
            pk[4] = (__bf16)((float)tw8[4] * th1[0]);
            pk[5] = (__bf16)((float)tw8[5] * th1[1]);
            pk[6] = (__bf16)((float)tw8[6] * th1[2]);
            pk[7] = (__bf16)((float)tw8[7] * th1[3]);

            acc[0] = __builtin_amdgcn_mfma_f32_16x16x32_bf16(af[0][ks], pk, acc[0], 0, 0, 0);
            acc[1] = __builtin_amdgcn_mfma_f32_16x16x32_bf16(af[1][ks], pk, acc[1], 0, 0, 0);
        }

        // ---- fused epilogue (fire-and-forget stores; no barrier follows) ----
#pragma unroll
        for (int mf = 0; mf < 2; ++mf) {
            const f32x4 pb4 = *(const f32x4*)(sPb + ob0 + mf * 16);
            const f32x4 po4 = *(const f32x4*)(sObj + ob0 + mf * 16);
#pragma unroll
            for (int r = 0; r < 4; ++r) {
                const int o = ob0 + mf * 16 + r;
                float v = acc[mf][r] + pb4[r];
                v = v * (1.f - ht) + po4[r] * ht;
                out[(((size_t)(b * O_ + o) * T_ + t) * H_ + hglb) * W_ +
                    w0 + l15] = v * mk;
            }
        }
    }
}

extern "C" void kernel_launch(void* const* d_in, const int* in_sizes, int n_in,
                              void* d_out, int out_size, void* d_ws, size_t ws_size,
                              hipStream_t stream) {
    const float* fea_th  = (const float*)d_in[0];
    const float* fea_tw  = (const float*)d_in[1];
    const float* fea_obj = (const float*)d_in[2];
    const float* heatmap = (const float*)d_in[3];
    const float* mask    = (const float*)d_in[4];
    const float* W3d     = (const float*)d_in[5];
    const float* b3d     = (const float*)d_in[6];
    const float* W1d     = (const float*)d_in[7];
    const float* b1d     = (const float*)d_in[8];
    float* out = (float*)d_out;

    hipLaunchKernelGGL(fused_kernel, dim3(1024), dim3(512), 0, stream,
                       fea_th, fea_tw, fea_obj, heatmap, mask,
                       W3d, b3d, W1d, b1d, out);
}

// Round 11
// 59.649 us; speedup vs baseline: 1.6934x; 1.6934x over previous
//
#include <hip/hip_runtime.h>
#include <hip/hip_bf16.h>

// Problem constants
#define B_ 2
#define C_ 256
#define O_ 256
#define T_ 16
#define H_ 64
#define W_ 64

typedef __bf16 bf16x8 __attribute__((ext_vector_type(8)));
typedef float  f32x4  __attribute__((ext_vector_type(4)));

// ---------------- single fused kernel (r9 structure + folded prep) ----------
// Grid 512 = wb(2) x hg(8) x bt(32). Block: 512 thr = 8 waves.
// Wave tile 32o x 32w; block covers 256 o x 32 w x 8 h.
// A (W3d): loaded per block straight from f32 global (L2-resident after
//   block 0; r10 measured FETCH=18.7MB total), cvt in-reg -> af[2][8]=64 VGPR.
// obj (1x1 conv1d): per-block 256x256 matvec from L2-resident W1d in the
//   prologue (replaces the serial prep kernel, ~6us saved).
// B (th*tw): built per h into 16KB swizzled LDS, double-buffered; order per
//   r9: {MFMA(h) || build(h+1)} -> sync -> store(h). One sync/h.
__global__ __attribute__((amdgpu_flat_work_group_size(512, 512)))
void fused_kernel(
    const float* __restrict__ fea_th, const float* __restrict__ fea_tw,
    const float* __restrict__ fea_obj,
    const float* __restrict__ heatmap, const float* __restrict__ mask,
    const float* __restrict__ W3d, const float* __restrict__ b3d,
    const float* __restrict__ W1d, const float* __restrict__ b1d,
    float* __restrict__ out) {
    __shared__ __align__(16) char smem[45056];
    char*  sB0  = smem;                      // [32 w][512 B] swizzled, buf 0
    char*  sB1  = smem + 16384;              // buf 1
    float* sTh  = (float*)(smem + 32768);    // [8 h][256 c] f32
    float* sPb  = (float*)(smem + 40960);    // [256] b3d
    float* sObj = (float*)(smem + 41984);    // [256] conv1d out for (b,t)
    float* sFo  = (float*)(smem + 43008);    // [256] fea_obj[b,:,t]

    const int tid  = threadIdx.x;
    const int lane = tid & 63;
    const int wv   = tid >> 6;       // 0..7 -> o base wv*32
    const int kgrp = lane >> 4;
    const int l15  = lane & 15;

    const int bid = blockIdx.x;
    const int wb = bid & 1, hg = (bid >> 1) & 7, bt = bid >> 4;
    const int b = bt >> 4, t = bt & 15;
    const int h0 = hg * 8, w0 = wb * 32;

    // ---- stage th / fo / pb (first 256 threads; c or o = tid) ----
    if (tid < 256) {
        const float* thp = fea_th + ((b * C_ + tid) * T_ + t) * H_ + h0;
        float4 v0 = *(const float4*)thp;
        float4 v1 = *(const float4*)(thp + 4);
        sTh[0 * 256 + tid] = v0.x;  sTh[1 * 256 + tid] = v0.y;
        sTh[2 * 256 + tid] = v0.z;  sTh[3 * 256 + tid] = v0.w;
        sTh[4 * 256 + tid] = v1.x;  sTh[5 * 256 + tid] = v1.y;
        sTh[6 * 256 + tid] = v1.z;  sTh[7 * 256 + tid] = v1.w;
        sFo[tid] = fea_obj[(b * C_ + tid) * T_ + t];
        sPb[tid] = b3d[tid];
    }

    // ---- tw -> per-thread bf16 slice (w = w0 + (tid&31), c in [cs, cs+16)) ----
    const int wl = tid & 31;
    const int cs = (tid >> 5) * 16;
    bf16x8 twb0, twb1;
    {
        const float* twp = fea_tw + ((b * C_ + cs) * T_ + t) * W_ + w0 + wl;
#pragma unroll
        for (int j = 0; j < 8; ++j) twb0[j] = (__bf16)twp[j * (T_ * W_)];
#pragma unroll
        for (int j = 0; j < 8; ++j) twb1[j] = (__bf16)twp[(8 + j) * (T_ * W_)];
    }

    // ---- A panel: W3d f32 -> bf16 regs, af[mf][ks] = 64 VGPR ----
    bf16x8 af[2][8];
#pragma unroll
    for (int mf = 0; mf < 2; ++mf)
#pragma unroll
        for (int ks = 0; ks < 8; ++ks) {
            const float* wp = W3d + (wv * 32 + mf * 16 + l15) * C_ +
                              ks * 32 + kgrp * 8;
            const f32x4 a0 = *(const f32x4*)wp;
            const f32x4 a1 = *(const f32x4*)(wp + 4);
            bf16x8 pk;
            pk[0] = (__bf16)a0[0]; pk[1] = (__bf16)a0[1];
            pk[2] = (__bf16)a0[2]; pk[3] = (__bf16)a0[3];
            pk[4] = (__bf16)a1[0]; pk[5] = (__bf16)a1[1];
            pk[6] = (__bf16)a1[2]; pk[7] = (__bf16)a1[3];
            af[mf][ks] = pk;
        }

    const int swzW = (wl & 7) << 4;
    const int c0g  = cs * 2;   // byte col of this thread's first 8-c group

    auto build = [&](int hl, char* dst) {
        const float* thp = sTh + hl * 256 + cs;
        const f32x4 t0 = *(const f32x4*)thp;
        const f32x4 t1 = *(const f32x4*)(thp + 4);
        const f32x4 t2 = *(const f32x4*)(thp + 8);
        const f32x4 t3 = *(const f32x4*)(thp + 12);
        bf16x8 z0, z1;
        z0[0] = (__bf16)((float)twb0[0] * t0[0]);
        z0[1] = (__bf16)((float)twb0[1] * t0[1]);
        z0[2] = (__bf16)((float)twb0[2] * t0[2]);
        z0[3] = (__bf16)((float)twb0[3] * t0[3]);
        z0[4] = (__bf16)((float)twb0[4] * t1[0]);
        z0[5] = (__bf16)((float)twb0[5] * t1[1]);
        z0[6] = (__bf16)((float)twb0[6] * t1[2]);
        z0[7] = (__bf16)((float)twb0[7] * t1[3]);
        z1[0] = (__bf16)((float)twb1[0] * t2[0]);
        z1[1] = (__bf16)((float)twb1[1] * t2[1]);
        z1[2] = (__bf16)((float)twb1[2] * t2[2]);
        z1[3] = (__bf16)((float)twb1[3] * t2[3]);
        z1[4] = (__bf16)((float)twb1[4] * t3[0]);
        z1[5] = (__bf16)((float)twb1[5] * t3[1]);
        z1[6] = (__bf16)((float)twb1[6] * t3[2]);
        z1[7] = (__bf16)((float)twb1[7] * t3[3]);
        *(bf16x8*)(dst + wl * 512 + (c0g ^ swzW))        = z0;
        *(bf16x8*)(dst + wl * 512 + ((c0g + 16) ^ swzW)) = z1;
    };

    __syncthreads();          // sTh / sFo / sPb ready

    // ---- obj[o] = dot(W1d[o,:], fo) + b1d[o]  (first 256 threads) ----
    if (tid < 256) {
        const float4* wrow = (const float4*)(W1d + tid * C_);
        float s = 0.f;
#pragma unroll 8
        for (int cq = 0; cq < C_ / 4; ++cq) {
            const float4 w4 = wrow[cq];
            s += w4.x * sFo[cq * 4 + 0] + w4.y * sFo[cq * 4 + 1] +
                 w4.z * sFo[cq * 4 + 2] + w4.w * sFo[cq * 4 + 3];
        }
        sObj[tid] = s + b1d[tid];
    }

    build(0, sB0);
    __syncthreads();          // sB0 + sObj ready

    const int hmb  = (b * T_ + t) * (H_ * W_);
    const int swzR = (l15 & 7) << 4;
    const int ob0  = wv * 32 + kgrp * 4;

    for (int hl = 0; hl < 8; ++hl) {
        char* cur = (hl & 1) ? sB1 : sB0;

        const int hglb = h0 + hl;
        const int hrow = hmb + hglb * W_ + w0 + l15;
        // issued early; consumed after the sync (latency fully hidden)
        const float ht0 = heatmap[hrow],      mk0 = mask[hrow];
        const float ht1 = heatmap[hrow + 16], mk1 = mask[hrow + 16];

        f32x4 acc[2][2] = {};
#pragma unroll
        for (int ks = 0; ks < 8; ++ks) {
            const int kb = ks * 64 + kgrp * 16;
            const bf16x8 b0 = *(const bf16x8*)(cur + l15 * 512 + (kb ^ swzR));
            const bf16x8 b1 = *(const bf16x8*)(cur + (16 + l15) * 512 + (kb ^ swzR));
            acc[0][0] = __builtin_amdgcn_mfma_f32_16x16x32_bf16(af[0][ks], b0, acc[0][0], 0, 0, 0);
            acc[0][1] = __builtin_amdgcn_mfma_f32_16x16x32_bf16(af[0][ks], b1, acc[0][1], 0, 0, 0);
            acc[1][0] = __builtin_amdgcn_mfma_f32_16x16x32_bf16(af[1][ks], b0, acc[1][0], 0, 0, 0);
            acc[1][1] = __builtin_amdgcn_mfma_f32_16x16x32_bf16(af[1][ks], b1, acc[1][1], 0, 0, 0);
        }

        if (hl < 7) build(hl + 1, (hl & 1) ? sB0 : sB1);

        // sync BEFORE the stores: drains ds ops + phase-old stores (cheap);
        // separates this iter's cur-reads from build(hl+2)'s overwrites.
        if (hl < 7) __syncthreads();

        // ---- fused epilogue (stores issued after the barrier) ----
#pragma unroll
        for (int mf = 0; mf < 2; ++mf) {
            const f32x4 pb4 = *(const f32x4*)(sPb + ob0 + mf * 16);
            const f32x4 po4 = *(const f32x4*)(sObj + ob0 + mf * 16);
#pragma unroll
            for (int r = 0; r < 4; ++r) {
                const int o = ob0 + mf * 16 + r;
                float* orow = out + (((size_t)(b * O_ + o) * T_ + t) * H_ + hglb) * W_ + w0;
                float v0 = acc[mf][0][r] + pb4[r];
                v0 = v0 * (1.f - ht0) + po4[r] * ht0;
                orow[l15] = v0 * mk0;
                float v1 = acc[mf][1][r] + pb4[r];
                v1 = v1 * (1.f - ht1) + po4[r] * ht1;
                orow[16 + l15] = v1 * mk1;
            }
        }
    }
}

extern "C" void kernel_launch(void* const* d_in, const int* in_sizes, int n_in,
                              void* d_out, int out_size, void* d_ws, size_t ws_size,
                              hipStream_t stream) {
    const float* fea_th  = (const float*)d_in[0];
    const float* fea_tw  = (const float*)d_in[1];
    const float* fea_obj = (const float*)d_in[2];
    const float* heatmap = (const float*)d_in[3];
    const float* mask    = (const float*)d_in[4];
    const float* W3d     = (const float*)d_in[5];
    const float* b3d     = (const float*)d_in[6];
    const float* W1d     = (const float*)d_in[7];
    const float* b1d     = (const float*)d_in[8];
    float* out = (float*)d_out;

    hipLaunchKernelGGL(fused_kernel, dim3(512), dim3(512), 0, stream,
                       fea_th, fea_tw, fea_obj, heatmap, mask,
                       W3d, b3d, W1d, b1d, out);
}

// Round 12
// 47.216 us; speedup vs baseline: 2.1393x; 1.2633x over previous
//
#include <hip/hip_runtime.h>
#include <hip/hip_bf16.h>

// Problem constants
#define B_ 2
#define C_ 256
#define O_ 256
#define T_ 16
#define H_ 64
#define W_ 64

typedef __bf16 bf16x8 __attribute__((ext_vector_type(8)));
typedef float  f32x4  __attribute__((ext_vector_type(4)));

// ws layout:
//   [0, 131072)       : W3d bf16 LINEAR image [256 o][256 c] (512 B rows)
//   [131072, 163840)  : obj f32 [b][t][o]
#define WS_OBJ_OFF 131072

// ---------------- prep kernel (identical to r9) ----------------
__global__ __launch_bounds__(256) void prep_kernel(
    const float* __restrict__ fea_obj, const float* __restrict__ W3d,
    const float* __restrict__ W1d, const float* __restrict__ b1d,
    __bf16* __restrict__ wsW, float* __restrict__ wsObj) {
    const int bid = blockIdx.x;
    const int tid = threadIdx.x;
    if (bid < 32) {
        const int b = bid >> 4, t = bid & 15;
        __shared__ float fo[C_];
        fo[tid] = fea_obj[(b * C_ + tid) * T_ + t];
        __syncthreads();
        const int o = tid;
        const float4* wrow = (const float4*)(W1d + o * C_);
        float s = 0.f;
#pragma unroll 8
        for (int cq = 0; cq < C_ / 4; ++cq) {
            float4 wv = wrow[cq];
            s += wv.x * fo[cq * 4 + 0] + wv.y * fo[cq * 4 + 1] +
                 wv.z * fo[cq * 4 + 2] + wv.w * fo[cq * 4 + 3];
        }
        wsObj[(b * T_ + t) * O_ + o] = s + b1d[o];
    } else {
        const int g = (bid - 32) * 256 + tid;
        const int o = g >> 5;
        const int cg = g & 31;
        const float* sp = W3d + o * C_ + cg * 8;
        float4 a0 = *(const float4*)sp;
        float4 a1 = *(const float4*)(sp + 4);
        bf16x8 pk;
        pk[0] = (__bf16)a0.x; pk[1] = (__bf16)a0.y;
        pk[2] = (__bf16)a0.z; pk[3] = (__bf16)a0.w;
        pk[4] = (__bf16)a1.x; pk[5] = (__bf16)a1.y;
        pk[6] = (__bf16)a1.z; pk[7] = (__bf16)a1.w;
        *(bf16x8*)((char*)wsW + o * 512 + cg * 16) = pk;
    }
}

// ---------------- main kernel ----------------
// Grid 512 = wb(2) x hg(8) x bt(32). Block: 512 thr = 8 waves.
// Wave tile 32o x 32w; A (W3d bf16 image) in regs af[2][8]=64 VGPR.
// B panel layout CHANGE vs r9: [cg(32 groups of 8 c)][w(32)][16B] -> build
// writes are 512B-contiguous wave stores, MFMA reads are 256B-contiguous
// quarter-wave reads: ZERO bank conflicts (r9 measured 2.1M conflict cyc),
// no swizzle VALU, and all ks-reads are base+imm-offset.
// Second change: 2h per barrier (4 panels, 74KB LDS): barriers 8 -> 4.
__global__ __attribute__((amdgpu_flat_work_group_size(512, 512)))
void main_kernel(
    const float* __restrict__ fea_th, const float* __restrict__ fea_tw,
    const float* __restrict__ heatmap, const float* __restrict__ mask,
    const float* __restrict__ b3d,
    const __bf16* __restrict__ wsW, const float* __restrict__ wsObj,
    float* __restrict__ out) {
    __shared__ __align__(16) char smem[75776];
    // panels: P0=0, P1=16384, P2=32768, P3=49152 (each [32 cg][32 w][16B])
    float* sTh  = (float*)(smem + 65536);    // [8 h][256 c] f32
    float* sPb  = (float*)(smem + 73728);    // [256] b3d
    float* sObj = (float*)(smem + 74752);    // [256] obj for this (b,t)

    const int tid  = threadIdx.x;
    const int lane = tid & 63;
    const int wv   = tid >> 6;       // 0..7 -> o base wv*32
    const int kgrp = lane >> 4;
    const int l15  = lane & 15;

    const int bid = blockIdx.x;
    const int wb = bid & 1, hg = (bid >> 1) & 7, bt = bid >> 4;
    const int b = bt >> 4, t = bt & 15;
    const int h0 = hg * 8, w0 = wb * 32;

    // ---- stage th / pb / obj (first 256 threads) ----
    const float* objp = wsObj + (b * T_ + t) * O_;
    if (tid < 256) {
        const float* thp = fea_th + ((b * C_ + tid) * T_ + t) * H_ + h0;
        float4 v0 = *(const float4*)thp;
        float4 v1 = *(const float4*)(thp + 4);
        sTh[0 * 256 + tid] = v0.x;  sTh[1 * 256 + tid] = v0.y;
        sTh[2 * 256 + tid] = v0.z;  sTh[3 * 256 + tid] = v0.w;
        sTh[4 * 256 + tid] = v1.x;  sTh[5 * 256 + tid] = v1.y;
        sTh[6 * 256 + tid] = v1.z;  sTh[7 * 256 + tid] = v1.w;
        sPb[tid]  = b3d[tid];
        sObj[tid] = objp[tid];
    }

    // ---- tw -> per-thread bf16 slice (w = w0 + (tid&31), c in [cs, cs+16)) ----
    const int wl = tid & 31;
    const int cs = (tid >> 5) * 16;
    bf16x8 twb0, twb1;
    {
        const float* twp = fea_tw + ((b * C_ + cs) * T_ + t) * W_ + w0 + wl;
#pragma unroll
        for (int j = 0; j < 8; ++j) twb0[j] = (__bf16)twp[j * (T_ * W_)];
#pragma unroll
        for (int j = 0; j < 8; ++j) twb1[j] = (__bf16)twp[(8 + j) * (T_ * W_)];
    }

    // ---- A panel -> registers: af[mf][ks], 64 VGPR ----
    bf16x8 af[2][8];
#pragma unroll
    for (int mf = 0; mf < 2; ++mf)
#pragma unroll
        for (int ks = 0; ks < 8; ++ks)
            af[mf][ks] = *(const bf16x8*)(
                wsW + (wv * 32 + mf * 16 + l15) * 256 + ks * 32 + kgrp * 8);

    // build: thread (wl, cs) -> cg0 = cs/8, conflict-free contiguous writes
    const int wbyte = wl * 16;
    const int cg0   = (tid >> 5) * 2;

    auto build = [&](int hl, char* dst) {
        const float* thp = sTh + hl * 256 + cs;
        const f32x4 t0 = *(const f32x4*)thp;
        const f32x4 t1 = *(const f32x4*)(thp + 4);
        const f32x4 t2 = *(const f32x4*)(thp + 8);
        const f32x4 t3 = *(const f32x4*)(thp + 12);
        bf16x8 z0, z1;
        z0[0] = (__bf16)((float)twb0[0] * t0[0]);
        z0[1] = (__bf16)((float)twb0[1] * t0[1]);
        z0[2] = (__bf16)((float)twb0[2] * t0[2]);
        z0[3] = (__bf16)((float)twb0[3] * t0[3]);
        z0[4] = (__bf16)((float)twb0[4] * t1[0]);
        z0[5] = (__bf16)((float)twb0[5] * t1[1]);
        z0[6] = (__bf16)((float)twb0[6] * t1[2]);
        z0[7] = (__bf16)((float)twb0[7] * t1[3]);
        z1[0] = (__bf16)((float)twb1[0] * t2[0]);
        z1[1] = (__bf16)((float)twb1[1] * t2[1]);
        z1[2] = (__bf16)((float)twb1[2] * t2[2]);
        z1[3] = (__bf16)((float)twb1[3] * t2[3]);
        z1[4] = (__bf16)((float)twb1[4] * t3[0]);
        z1[5] = (__bf16)((float)twb1[5] * t3[1]);
        z1[6] = (__bf16)((float)twb1[6] * t3[2]);
        z1[7] = (__bf16)((float)twb1[7] * t3[3]);
        *(bf16x8*)(dst + cg0 * 512 + wbyte)       = z0;
        *(bf16x8*)(dst + (cg0 + 1) * 512 + wbyte) = z1;
    };

    __syncthreads();          // sTh / sPb / sObj ready
    build(0, smem);
    build(1, smem + 16384);
    __syncthreads();          // pair 0 ready

    const int hmb = (b * T_ + t) * (H_ * W_);
    const int ob0 = wv * 32 + kgrp * 4;
    const int rb  = kgrp * 512 + l15 * 16;   // read base within a panel

    for (int p = 0; p < 4; ++p) {
        char* curA = smem + ((p & 1) ? 32768 : 0);
        char* curB = curA + 16384;
        char* nxtA = smem + ((p & 1) ? 0 : 32768);
        char* nxtB = nxtA + 16384;
        const int hA = h0 + 2 * p, hB = hA + 1;

        const int rowA = hmb + hA * W_ + w0 + l15;
        const int rowB = hmb + hB * W_ + w0 + l15;
        const float htA0 = heatmap[rowA],      mkA0 = mask[rowA];
        const float htA1 = heatmap[rowA + 16], mkA1 = mask[rowA + 16];
        const float htB0 = heatmap[rowB],      mkB0 = mask[rowB];
        const float htB1 = heatmap[rowB + 16], mkB1 = mask[rowB + 16];

        // ---- h = hA: MFMA from curA ----
        f32x4 acc[2][2] = {};
#pragma unroll
        for (int ks = 0; ks < 8; ++ks) {
            const bf16x8 b0 = *(const bf16x8*)(curA + rb + ks * 2048);
            const bf16x8 b1 = *(const bf16x8*)(curA + rb + ks * 2048 + 256);
            acc[0][0] = __builtin_amdgcn_mfma_f32_16x16x32_bf16(af[0][ks], b0, acc[0][0], 0, 0, 0);
            acc[0][1] = __builtin_amdgcn_mfma_f32_16x16x32_bf16(af[0][ks], b1, acc[0][1], 0, 0, 0);
            acc[1][0] = __builtin_amdgcn_mfma_f32_16x16x32_bf16(af[1][ks], b0, acc[1][0], 0, 0, 0);
            acc[1][1] = __builtin_amdgcn_mfma_f32_16x16x32_bf16(af[1][ks], b1, acc[1][1], 0, 0, 0);
        }
        if (p < 3) build(2 * p + 2, nxtA);
#pragma unroll
        for (int mf = 0; mf < 2; ++mf) {
            const f32x4 pb4 = *(const f32x4*)(sPb + ob0 + mf * 16);
            const f32x4 po4 = *(const f32x4*)(sObj + ob0 + mf * 16);
#pragma unroll
            for (int r = 0; r < 4; ++r) {
                const int o = ob0 + mf * 16 + r;
                float* orow = out + (((size_t)(b * O_ + o) * T_ + t) * H_ + hA) * W_ + w0;
                float v0 = acc[mf][0][r] + pb4[r];
                v0 = v0 * (1.f - htA0) + po4[r] * htA0;
                orow[l15] = v0 * mkA0;
                float v1 = acc[mf][1][r] + pb4[r];
                v1 = v1 * (1.f - htA1) + po4[r] * htA1;
                orow[16 + l15] = v1 * mkA1;
            }
        }

        // ---- h = hB: MFMA from curB ----
        f32x4 acd[2][2] = {};
#pragma unroll
        for (int ks = 0; ks < 8; ++ks) {
            const bf16x8 b0 = *(const bf16x8*)(curB + rb + ks * 2048);
            const bf16x8 b1 = *(const bf16x8*)(curB + rb + ks * 2048 + 256);
            acd[0][0] = __builtin_amdgcn_mfma_f32_16x16x32_bf16(af[0][ks], b0, acd[0][0], 0, 0, 0);
            acd[0][1] = __builtin_amdgcn_mfma_f32_16x16x32_bf16(af[0][ks], b1, acd[0][1], 0, 0, 0);
            acd[1][0] = __builtin_amdgcn_mfma_f32_16x16x32_bf16(af[1][ks], b0, acd[1][0], 0, 0, 0);
            acd[1][1] = __builtin_amdgcn_mfma_f32_16x16x32_bf16(af[1][ks], b1, acd[1][1], 0, 0, 0);
        }
        if (p < 3) build(2 * p + 3, nxtB);
#pragma unroll
        for (int mf = 0; mf < 2; ++mf) {
            const f32x4 pb4 = *(const f32x4*)(sPb + ob0 + mf * 16);
            const f32x4 po4 = *(const f32x4*)(sObj + ob0 + mf * 16);
#pragma unroll
            for (int r = 0; r < 4; ++r) {
                const int o = ob0 + mf * 16 + r;
                float* orow = out + (((size_t)(b * O_ + o) * T_ + t) * H_ + hB) * W_ + w0;
                float v0 = acd[mf][0][r] + pb4[r];
                v0 = v0 * (1.f - htB0) + po4[r] * htB0;
                orow[l15] = v0 * mkB0;
                float v1 = acd[mf][1][r] + pb4[r];
                v1 = v1 * (1.f - htB1) + po4[r] * htB1;
                orow[16 + l15] = v1 * mkB1;
            }
        }

        if (p < 3) __syncthreads();   // pair p reads done; pair p+1 buffers built
    }
}

extern "C" void kernel_launch(void* const* d_in, const int* in_sizes, int n_in,
                              void* d_out, int out_size, void* d_ws, size_t ws_size,
                              hipStream_t stream) {
    const float* fea_th  = (const float*)d_in[0];
    const float* fea_tw  = (const float*)d_in[1];
    const float* fea_obj = (const float*)d_in[2];
    const float* heatmap = (const float*)d_in[3];
    const float* mask    = (const float*)d_in[4];
    const float* W3d     = (const float*)d_in[5];
    const float* b3d     = (const float*)d_in[6];
    const float* W1d     = (const float*)d_in[7];
    const float* b1d     = (const float*)d_in[8];
    float* out = (float*)d_out;

    __bf16* wsW  = (__bf16*)d_ws;
    float* wsObj = (float*)((char*)d_ws + WS_OBJ_OFF);

    hipLaunchKernelGGL(prep_kernel, dim3(64), dim3(256), 0, stream,
                       fea_obj, W3d, W1d, b1d, wsW, wsObj);
    hipLaunchKernelGGL(main_kernel, dim3(512), dim3(512), 0, stream,
                       fea_th, fea_tw, heatmap, mask, b3d, wsW, wsObj, out);
}

// Round 13
// 47.115 us; speedup vs baseline: 2.1439x; 1.0022x over previous
//
#include <hip/hip_runtime.h>
#include <hip/hip_bf16.h>

// Problem constants
#define B_ 2
#define C_ 256
#define O_ 256
#define T_ 16
#define H_ 64
#define W_ 64

typedef __bf16 bf16x8 __attribute__((ext_vector_type(8)));
typedef float  f32x4  __attribute__((ext_vector_type(4)));

// ws layout:
//   [0, 131072)       : W3d bf16 LINEAR image [256 o][256 c] (512 B rows)
//   [131072, 163840)  : obj f32 [b][t][o]
#define WS_OBJ_OFF 131072

// LDS-only barrier: orders ds_write/ds_read across waves WITHOUT draining
// the vmem store queue (__syncthreads emits s_waitcnt vmcnt(0) which stalls
// all waves on the output stores). lgkmcnt(0) completes this wave's LDS ops;
// s_barrier (hasSideEffects) orders across waves; trailing empty asm blocks
// IR-level motion of LDS ops above the barrier without sched_barrier's
// scheduler pinning (r8 lesson).
__device__ __forceinline__ void barrier_lds_only() {
    asm volatile("s_waitcnt lgkmcnt(0)" ::: "memory");
    __builtin_amdgcn_s_barrier();
    asm volatile("" ::: "memory");
}

// ---------------- prep kernel (identical to r9/r12) ----------------
__global__ __launch_bounds__(256) void prep_kernel(
    const float* __restrict__ fea_obj, const float* __restrict__ W3d,
    const float* __restrict__ W1d, const float* __restrict__ b1d,
    __bf16* __restrict__ wsW, float* __restrict__ wsObj) {
    const int bid = blockIdx.x;
    const int tid = threadIdx.x;
    if (bid < 32) {
        const int b = bid >> 4, t = bid & 15;
        __shared__ float fo[C_];
        fo[tid] = fea_obj[(b * C_ + tid) * T_ + t];
        __syncthreads();
        const int o = tid;
        const float4* wrow = (const float4*)(W1d + o * C_);
        float s = 0.f;
#pragma unroll 8
        for (int cq = 0; cq < C_ / 4; ++cq) {
            float4 wv = wrow[cq];
            s += wv.x * fo[cq * 4 + 0] + wv.y * fo[cq * 4 + 1] +
                 wv.z * fo[cq * 4 + 2] + wv.w * fo[cq * 4 + 3];
        }
        wsObj[(b * T_ + t) * O_ + o] = s + b1d[o];
    } else {
        const int g = (bid - 32) * 256 + tid;
        const int o = g >> 5;
        const int cg = g & 31;
        const float* sp = W3d + o * C_ + cg * 8;
        float4 a0 = *(const float4*)sp;
        float4 a1 = *(const float4*)(sp + 4);
        bf16x8 pk;
        pk[0] = (__bf16)a0.x; pk[1] = (__bf16)a0.y;
        pk[2] = (__bf16)a0.z; pk[3] = (__bf16)a0.w;
        pk[4] = (__bf16)a1.x; pk[5] = (__bf16)a1.y;
        pk[6] = (__bf16)a1.z; pk[7] = (__bf16)a1.w;
        *(bf16x8*)((char*)wsW + o * 512 + cg * 16) = pk;
    }
}

// ---------------- main kernel (r12 structure, LDS-only in-loop barriers) ----
// Grid 512 = wb(2) x hg(8) x bt(32). Block: 512 thr = 8 waves.
// Wave tile 32o x 32w; A (W3d bf16 image) in regs af[2][8]=64 VGPR.
// B panel [cg(32)][w(32)][16B]: conflict-free build-writes and reads.
// 2h per barrier (4 panels, 74KB LDS); in-loop barriers are LDS-only so
// output stores never stall a barrier (r13's single change vs r12).
__global__ __attribute__((amdgpu_flat_work_group_size(512, 512)))
void main_kernel(
    const float* __restrict__ fea_th, const float* __restrict__ fea_tw,
    const float* __restrict__ heatmap, const float* __restrict__ mask,
    const float* __restrict__ b3d,
    const __bf16* __restrict__ wsW, const float* __restrict__ wsObj,
    float* __restrict__ out) {
    __shared__ __align__(16) char smem[75776];
    // panels: P0=0, P1=16384, P2=32768, P3=49152 (each [32 cg][32 w][16B])
    float* sTh  = (float*)(smem + 65536);    // [8 h][256 c] f32
    float* sPb  = (float*)(smem + 73728);    // [256] b3d
    float* sObj = (float*)(smem + 74752);    // [256] obj for this (b,t)

    const int tid  = threadIdx.x;
    const int lane = tid & 63;
    const int wv   = tid >> 6;       // 0..7 -> o base wv*32
    const int kgrp = lane >> 4;
    const int l15  = lane & 15;

    const int bid = blockIdx.x;
    const int wb = bid & 1, hg = (bid >> 1) & 7, bt = bid >> 4;
    const int b = bt >> 4, t = bt & 15;
    const int h0 = hg * 8, w0 = wb * 32;

    // ---- stage th / pb / obj (first 256 threads) ----
    const float* objp = wsObj + (b * T_ + t) * O_;
    if (tid < 256) {
        const float* thp = fea_th + ((b * C_ + tid) * T_ + t) * H_ + h0;
        float4 v0 = *(const float4*)thp;
        float4 v1 = *(const float4*)(thp + 4);
        sTh[0 * 256 + tid] = v0.x;  sTh[1 * 256 + tid] = v0.y;
        sTh[2 * 256 + tid] = v0.z;  sTh[3 * 256 + tid] = v0.w;
        sTh[4 * 256 + tid] = v1.x;  sTh[5 * 256 + tid] = v1.y;
        sTh[6 * 256 + tid] = v1.z;  sTh[7 * 256 + tid] = v1.w;
        sPb[tid]  = b3d[tid];
        sObj[tid] = objp[tid];
    }

    // ---- tw -> per-thread bf16 slice (w = w0 + (tid&31), c in [cs, cs+16)) ----
    const int wl = tid & 31;
    const int cs = (tid >> 5) * 16;
    bf16x8 twb0, twb1;
    {
        const float* twp = fea_tw + ((b * C_ + cs) * T_ + t) * W_ + w0 + wl;
#pragma unroll
        for (int j = 0; j < 8; ++j) twb0[j] = (__bf16)twp[j * (T_ * W_)];
#pragma unroll
        for (int j = 0; j < 8; ++j) twb1[j] = (__bf16)twp[(8 + j) * (T_ * W_)];
    }

    // ---- A panel -> registers: af[mf][ks], 64 VGPR ----
    bf16x8 af[2][8];
#pragma unroll
    for (int mf = 0; mf < 2; ++mf)
#pragma unroll
        for (int ks = 0; ks < 8; ++ks)
            af[mf][ks] = *(const bf16x8*)(
                wsW + (wv * 32 + mf * 16 + l15) * 256 + ks * 32 + kgrp * 8);

    // build: thread (wl, cs) -> cg0 = cs/8, conflict-free contiguous writes
    const int wbyte = wl * 16;
    const int cg0   = (tid >> 5) * 2;

    auto build = [&](int hl, char* dst) {
        const float* thp = sTh + hl * 256 + cs;
        const f32x4 t0 = *(const f32x4*)thp;
        const f32x4 t1 = *(const f32x4*)(thp + 4);
        const f32x4 t2 = *(const f32x4*)(thp + 8);
        const f32x4 t3 = *(const f32x4*)(thp + 12);
        bf16x8 z0, z1;
        z0[0] = (__bf16)((float)twb0[0] * t0[0]);
        z0[1] = (__bf16)((float)twb0[1] * t0[1]);
        z0[2] = (__bf16)((float)twb0[2] * t0[2]);
        z0[3] = (__bf16)((float)twb0[3] * t0[3]);
        z0[4] = (__bf16)((float)twb0[4] * t1[0]);
        z0[5] = (__bf16)((float)twb0[5] * t1[1]);
        z0[6] = (__bf16)((float)twb0[6] * t1[2]);
        z0[7] = (__bf16)((float)twb0[7] * t1[3]);
        z1[0] = (__bf16)((float)twb1[0] * t2[0]);
        z1[1] = (__bf16)((float)twb1[1] * t2[1]);
        z1[2] = (__bf16)((float)twb1[2] * t2[2]);
        z1[3] = (__bf16)((float)twb1[3] * t2[3]);
        z1[4] = (__bf16)((float)twb1[4] * t3[0]);
        z1[5] = (__bf16)((float)twb1[5] * t3[1]);
        z1[6] = (__bf16)((float)twb1[6] * t3[2]);
        z1[7] = (__bf16)((float)twb1[7] * t3[3]);
        *(bf16x8*)(dst + cg0 * 512 + wbyte)       = z0;
        *(bf16x8*)(dst + (cg0 + 1) * 512 + wbyte) = z1;
    };

    __syncthreads();          // sTh / sPb / sObj ready (prologue: full sync ok)
    build(0, smem);
    build(1, smem + 16384);
    __syncthreads();          // pair 0 ready

    const int hmb = (b * T_ + t) * (H_ * W_);
    const int ob0 = wv * 32 + kgrp * 4;
    const int rb  = kgrp * 512 + l15 * 16;   // read base within a panel

    for (int p = 0; p < 4; ++p) {
        char* curA = smem + ((p & 1) ? 32768 : 0);
        char* curB = curA + 16384;
        char* nxtA = smem + ((p & 1) ? 0 : 32768);
        char* nxtB = nxtA + 16384;
        const int hA = h0 + 2 * p, hB = hA + 1;

        const int rowA = hmb + hA * W_ + w0 + l15;
        const int rowB = hmb + hB * W_ + w0 + l15;
        const float htA0 = heatmap[rowA],      mkA0 = mask[rowA];
        const float htA1 = heatmap[rowA + 16], mkA1 = mask[rowA + 16];
        const float htB0 = heatmap[rowB],      mkB0 = mask[rowB];
        const float htB1 = heatmap[rowB + 16], mkB1 = mask[rowB + 16];

        // ---- h = hA: MFMA from curA ----
        f32x4 acc[2][2] = {};
#pragma unroll
        for (int ks = 0; ks < 8; ++ks) {
            const bf16x8 b0 = *(const bf16x8*)(curA + rb + ks * 2048);
            const bf16x8 b1 = *(const bf16x8*)(curA + rb + ks * 2048 + 256);
            acc[0][0] = __builtin_amdgcn_mfma_f32_16x16x32_bf16(af[0][ks], b0, acc[0][0], 0, 0, 0);
            acc[0][1] = __builtin_amdgcn_mfma_f32_16x16x32_bf16(af[0][ks], b1, acc[0][1], 0, 0, 0);
            acc[1][0] = __builtin_amdgcn_mfma_f32_16x16x32_bf16(af[1][ks], b0, acc[1][0], 0, 0, 0);
            acc[1][1] = __builtin_amdgcn_mfma_f32_16x16x32_bf16(af[1][ks], b1, acc[1][1], 0, 0, 0);
        }
        if (p < 3) build(2 * p + 2, nxtA);
#pragma unroll
        for (int mf = 0; mf < 2; ++mf) {
            const f32x4 pb4 = *(const f32x4*)(sPb + ob0 + mf * 16);
            const f32x4 po4 = *(const f32x4*)(sObj + ob0 + mf * 16);
#pragma unroll
            for (int r = 0; r < 4; ++r) {
                const int o = ob0 + mf * 16 + r;
                float* orow = out + (((size_t)(b * O_ + o) * T_ + t) * H_ + hA) * W_ + w0;
                float v0 = acc[mf][0][r] + pb4[r];
                v0 = v0 * (1.f - htA0) + po4[r] * htA0;
                orow[l15] = v0 * mkA0;
                float v1 = acc[mf][1][r] + pb4[r];
                v1 = v1 * (1.f - htA1) + po4[r] * htA1;
                orow[16 + l15] = v1 * mkA1;
            }
        }

        // ---- h = hB: MFMA from curB ----
        f32x4 acd[2][2] = {};
#pragma unroll
        for (int ks = 0; ks < 8; ++ks) {
            const bf16x8 b0 = *(const bf16x8*)(curB + rb + ks * 2048);
            const bf16x8 b1 = *(const bf16x8*)(curB + rb + ks * 2048 + 256);
            acd[0][0] = __builtin_amdgcn_mfma_f32_16x16x32_bf16(af[0][ks], b0, acd[0][0], 0, 0, 0);
            acd[0][1] = __builtin_amdgcn_mfma_f32_16x16x32_bf16(af[0][ks], b1, acd[0][1], 0, 0, 0);
            acd[1][0] = __builtin_amdgcn_mfma_f32_16x16x32_bf16(af[1][ks], b0, acd[1][0], 0, 0, 0);
            acd[1][1] = __builtin_amdgcn_mfma_f32_16x16x32_bf16(af[1][ks], b1, acd[1][1], 0, 0, 0);
        }
        if (p < 3) build(2 * p + 3, nxtB);
#pragma unroll
        for (int mf = 0; mf < 2; ++mf) {
            const f32x4 pb4 = *(const f32x4*)(sPb + ob0 + mf * 16);
            const f32x4 po4 = *(const f32x4*)(sObj + ob0 + mf * 16);
#pragma unroll
            for (int r = 0; r < 4; ++r) {
                const int o = ob0 + mf * 16 + r;
                float* orow = out + (((size_t)(b * O_ + o) * T_ + t) * H_ + hB) * W_ + w0;
                float v0 = acd[mf][0][r] + pb4[r];
                v0 = v0 * (1.f - htB0) + po4[r] * htB0;
                orow[l15] = v0 * mkB0;
                float v1 = acd[mf][1][r] + pb4[r];
                v1 = v1 * (1.f - htB1) + po4[r] * htB1;
                orow[16 + l15] = v1 * mkB1;
            }
        }

        if (p < 3) barrier_lds_only();   // LDS-only: stores keep flowing
    }
}

extern "C" void kernel_launch(void* const* d_in, const int* in_sizes, int n_in,
                              void* d_out, int out_size, void* d_ws, size_t ws_size,
                              hipStream_t stream) {
    const float* fea_th  = (const float*)d_in[0];
    const float* fea_tw  = (const float*)d_in[1];
    const float* fea_obj = (const float*)d_in[2];
    const float* heatmap = (const float*)d_in[3];
    const float* mask    = (const float*)d_in[4];
    const float* W3d     = (const float*)d_in[5];
    const float* b3d     = (const float*)d_in[6];
    const float* W1d     = (const float*)d_in[7];
    const float* b1d     = (const float*)d_in[8];
    float* out = (float*)d_out;

    __bf16* wsW  = (__bf16*)d_ws;
    float* wsObj = (float*)((char*)d_ws + WS_OBJ_OFF);

    hipLaunchKernelGGL(prep_kernel, dim3(64), dim3(256), 0, stream,
                       fea_obj, W3d, W1d, b1d, wsW, wsObj);
    hipLaunchKernelGGL(main_kernel, dim3(512), dim3(512), 0, stream,
                       fea_th, fea_tw, heatmap, mask, b3d, wsW, wsObj, out);
}